// Round 1
// baseline (14495.436 us; speedup 1.0000x reference)
//
#include <hip/hip_runtime.h>
#include <math.h>

// Problem constants (fixed by the reference)
#define NN 4096
#define EE 65536
#define HDIM 256

typedef _Float16 f16;
typedef f16 f16x2 __attribute__((ext_vector_type(2)));

__device__ inline float fdot2f(f16x2 a, f16x2 b, float c) {
#if __has_builtin(__builtin_amdgcn_fdot2)
  return __builtin_amdgcn_fdot2(a, b, c, false);
#else
  return c + (float)a.x * (float)b.x + (float)a.y * (float)b.y;
#endif
}

__device__ inline float sigmoidf_(float x) { return 1.0f / (1.0f + __expf(-x)); }
__device__ inline float tanh_fast(float x) { return 1.0f - 2.0f / (__expf(2.0f * x) + 1.0f); }

// ---------------------------------------------------------------- GAT1 projection
// xl1 = x@Wl1+bl1 ; xr1 = x@Wr1+br1   (K=14, fused)
__global__ __launch_bounds__(256) void gat1_proj_kernel(
    const float* __restrict__ x,
    const float* __restrict__ Wl, const float* __restrict__ bl,
    const float* __restrict__ Wr, const float* __restrict__ br,
    float* __restrict__ xl1, float* __restrict__ xr1)
{
  const int m = blockIdx.y;
  const int n = blockIdx.x * 256 + threadIdx.x;
  __shared__ float xs[14];
  if (threadIdx.x < 14) xs[threadIdx.x] = x[m * 14 + threadIdx.x];
  __syncthreads();
  float a = bl[n], b = br[n];
#pragma unroll
  for (int k = 0; k < 14; ++k) {
    a = fmaf(xs[k], Wl[k * 1024 + n], a);
    b = fmaf(xs[k], Wr[k * 1024 + n], b);
  }
  xl1[m * 1024 + n] = a;
  xr1[m * 1024 + n] = b;
}

// ---------------------------------------------------------------- CSR build
__global__ void zero_kernel(int* __restrict__ p, int n) {
  int i = blockIdx.x * 256 + threadIdx.x;
  if (i < n) p[i] = 0;
}
__global__ void hist_kernel(const int* __restrict__ dst, int* __restrict__ counts) {
  int e = blockIdx.x * 256 + threadIdx.x;
  if (e < EE) atomicAdd(&counts[dst[e]], 1);
}
__global__ __launch_bounds__(1024) void scan_kernel(const int* __restrict__ counts,
                                                    int* __restrict__ rowptr) {
  __shared__ int s[1024];
  const int t = threadIdx.x;
  const int base = t * 4;
  int v[4];
  int sum = 0;
#pragma unroll
  for (int i = 0; i < 4; ++i) { v[i] = counts[base + i]; sum += v[i]; }
  s[t] = sum;
  __syncthreads();
  for (int off = 1; off < 1024; off <<= 1) {
    int x = (t >= off) ? s[t - off] : 0;
    __syncthreads();
    s[t] += x;
    __syncthreads();
  }
  int run = (t == 0) ? 0 : s[t - 1];
#pragma unroll
  for (int i = 0; i < 4; ++i) { rowptr[base + i] = run; run += v[i]; }
  if (t == 1023) rowptr[4096] = s[1023];
}
__global__ void copy_kernel(const int* __restrict__ a, int* __restrict__ b, int n) {
  int i = blockIdx.x * 256 + threadIdx.x;
  if (i < n) b[i] = a[i];
}
__global__ void scatter_kernel(const int* __restrict__ dst, int* __restrict__ cursor,
                               int* __restrict__ eids) {
  int e = blockIdx.x * 256 + threadIdx.x;
  if (e < EE) {
    int p = atomicAdd(&cursor[dst[e]], 1);
    eids[p] = e;
  }
}
// insertion-sort each dst's edge list -> deterministic FP accumulation order
__global__ void sortlists_kernel(const int* __restrict__ rowptr, int* __restrict__ eids) {
  int d = blockIdx.x * 256 + threadIdx.x;
  if (d >= NN) return;
  const int lo = rowptr[d], hi = rowptr[d + 1];
  for (int i = lo + 1; i < hi; ++i) {
    int key = eids[i];
    int k = i - 1;
    while (k >= lo && eids[k] > key) { eids[k + 1] = eids[k]; --k; }
    eids[k + 1] = key;
  }
}

// ---------------------------------------------------------------- edge logits
// one wave per (edge, head): logit = att[h] . leaky_relu(xl[src,h,:] + xr[dst,h,:])
template <int H>
__global__ __launch_bounds__(256) void edge_logits_kernel(
    const float* __restrict__ xl, const float* __restrict__ xr,
    const float* __restrict__ att, const int* __restrict__ ei,
    float* __restrict__ logits)
{
  const int wid = threadIdx.x >> 6;
  const int lane = threadIdx.x & 63;
  const int task = blockIdx.x * 4 + wid;  // = e*H + h, grid sized exactly
  const int e = task / H;
  const int h = task % H;
  const int src = ei[e];
  const int dst = ei[EE + e];
  const float4 a = reinterpret_cast<const float4*>(xl + (src * H + h) * HDIM)[lane];
  const float4 b = reinterpret_cast<const float4*>(xr + (dst * H + h) * HDIM)[lane];
  const float4 w = reinterpret_cast<const float4*>(att + h * HDIM)[lane];
  float v, acc = 0.f;
  v = a.x + b.x; acc += w.x * (v > 0.f ? v : 0.2f * v);
  v = a.y + b.y; acc += w.y * (v > 0.f ? v : 0.2f * v);
  v = a.z + b.z; acc += w.z * (v > 0.f ? v : 0.2f * v);
  v = a.w + b.w; acc += w.w * (v > 0.f ? v : 0.2f * v);
#pragma unroll
  for (int off = 32; off > 0; off >>= 1) acc += __shfl_down(acc, off, 64);
  if (lane == 0) logits[task] = acc;
}

// ---------------------------------------------------------------- GAT aggregate
// one block per dst node: softmax over incoming edges + weighted sum of xl[src],
// + bias, + relu.
template <int H, int VPT>
__global__ __launch_bounds__(256) void gat_agg_kernel(
    const float* __restrict__ xl, const float* __restrict__ logits,
    const int* __restrict__ src_arr, const int* __restrict__ rowptr,
    const int* __restrict__ eids, const float* __restrict__ bias,
    float* __restrict__ out)
{
  const int d = blockIdx.x;
  const int t = threadIdx.x;
  const int TPH = 256 / H;
  const int h = t / TPH;
  const int cb = (t % TPH) * VPT;
  const int ro = rowptr[d];
  const int L = rowptr[d + 1] - ro;

  float m = -INFINITY;
  for (int i = 0; i < L; ++i) m = fmaxf(m, logits[eids[ro + i] * H + h]);
  float denom = 1e-16f;
  for (int i = 0; i < L; ++i) denom += __expf(logits[eids[ro + i] * H + h] - m);
  const float inv = 1.0f / denom;

  float acc[VPT];
#pragma unroll
  for (int v = 0; v < VPT; ++v) acc[v] = 0.f;
  for (int i = 0; i < L; ++i) {
    const int e = eids[ro + i];
    const float p = __expf(logits[e * H + h] - m) * inv;
    const float* px = &xl[(src_arr[e] * H + h) * HDIM + cb];
    if constexpr (VPT == 4) {
      const float4 xv = *reinterpret_cast<const float4*>(px);
      acc[0] += p * xv.x; acc[1] += p * xv.y; acc[2] += p * xv.z; acc[3] += p * xv.w;
    } else {
      const float2 xv = *reinterpret_cast<const float2*>(px);
      acc[0] += p * xv.x; acc[1] += p * xv.y;
    }
  }
#pragma unroll
  for (int v = 0; v < VPT; ++v) {
    const float r = acc[v] + bias[h * HDIM + cb + v];
    out[d * (H * HDIM) + h * HDIM + cb + v] = fmaxf(r, 0.f);
  }
}

// ---------------------------------------------------------------- generic fp32 GEMM
// C[M,N] = act(A[M,K] @ B[K,N] + bias).  ACT: 0 none, 1 relu, 2 elu.
// BM=BN=64, BK=16, 256 threads, 4x4 per-thread tile. M%64==0, N%64==0, K%16==0.
template <int ACT>
__global__ __launch_bounds__(256) void gemm_kernel(
    const float* __restrict__ A, const float* __restrict__ B,
    const float* __restrict__ bias, float* __restrict__ C,
    int M, int N, int K)
{
  __shared__ float As[16][64];
  __shared__ float Bs[16][64];
  const int tid = threadIdx.x;
  const int tx = tid & 15, ty = tid >> 4;
  const int arow = blockIdx.y * 64;
  const int bcol = blockIdx.x * 64;
  const int a_r = tid >> 2;
  const int a_k4 = (tid & 3) * 4;
  const int b_k = tid >> 4;
  const int b_c = (tid & 15) * 4;

  float acc[4][4];
#pragma unroll
  for (int i = 0; i < 4; ++i)
#pragma unroll
    for (int j = 0; j < 4; ++j) acc[i][j] = 0.f;

  for (int k0 = 0; k0 < K; k0 += 16) {
    const float4 av = *reinterpret_cast<const float4*>(&A[(size_t)(arow + a_r) * K + k0 + a_k4]);
    const float4 bv = *reinterpret_cast<const float4*>(&B[(size_t)(k0 + b_k) * N + bcol + b_c]);
    __syncthreads();
    As[a_k4 + 0][a_r] = av.x;
    As[a_k4 + 1][a_r] = av.y;
    As[a_k4 + 2][a_r] = av.z;
    As[a_k4 + 3][a_r] = av.w;
    *reinterpret_cast<float4*>(&Bs[b_k][b_c]) = bv;
    __syncthreads();
#pragma unroll
    for (int k = 0; k < 16; ++k) {
      const float4 a4 = *reinterpret_cast<const float4*>(&As[k][ty * 4]);
      const float4 b4 = *reinterpret_cast<const float4*>(&Bs[k][tx * 4]);
      const float ar[4] = {a4.x, a4.y, a4.z, a4.w};
      const float br[4] = {b4.x, b4.y, b4.z, b4.w};
#pragma unroll
      for (int i = 0; i < 4; ++i)
#pragma unroll
        for (int j = 0; j < 4; ++j) acc[i][j] = fmaf(ar[i], br[j], acc[i][j]);
    }
  }
#pragma unroll
  for (int i = 0; i < 4; ++i) {
    const size_t r = arow + ty * 4 + i;
#pragma unroll
    for (int j = 0; j < 4; ++j) {
      const int ccol = bcol + tx * 4 + j;
      float v = acc[i][j] + bias[ccol];
      if (ACT == 1) v = fmaxf(v, 0.f);
      if (ACT == 2) v = v > 0.f ? v : __expf(v) - 1.f;
      C[r * N + ccol] = v;
    }
  }
}

// ---------------------------------------------------------------- BiLSTM
// grid = 2 blocks (one per direction), 256 threads (1 wave/SIMD).
// Thread j owns hidden element j: all 4 gate columns {g*256+j}.
// Whh as packed f16 pairs: PV pairs in VGPRs (4*PV regs), PL pairs in LDS.
#define PV 96
#define PL 32

__global__ __launch_bounds__(256, 1) void lstm_kernel(
    const float* __restrict__ gi_f, const float* __restrict__ gi_b,
    const float* __restrict__ Whh_f, const float* __restrict__ Whh_b,
    float* __restrict__ hcat)
{
  const int dir = blockIdx.x;
  const float* __restrict__ gi = dir ? gi_b : gi_f;
  const float* __restrict__ W = dir ? Whh_b : Whh_f;
  const int j = threadIdx.x;

  __shared__ uint4 wlds[PL / 4][4][256];                // 128 KiB
  __shared__ __align__(16) unsigned int hbuf[2][128];   // 1 KiB (h as packed f16x2)

  // LDS-resident weight pairs p = PV..127, layout [chunk][gate][thread] (uint4 = 4 pairs)
#pragma unroll
  for (int ch = 0; ch < PL / 4; ++ch) {
#pragma unroll
    for (int g = 0; g < 4; ++g) {
      uint4 wv;
      unsigned* wp = reinterpret_cast<unsigned*>(&wv);
#pragma unroll
      for (int pi = 0; pi < 4; ++pi) {
        const int p = PV + ch * 4 + pi;
        f16x2 w;
        w.x = (f16)W[(2 * p) * 1024 + g * 256 + j];
        w.y = (f16)W[(2 * p + 1) * 1024 + g * 256 + j];
        wp[pi] = __builtin_bit_cast(unsigned, w);
      }
      wlds[ch][g][j] = wv;
    }
  }

  // VGPR-resident weight pairs p = 0..PV-1
  f16x2 wreg[4][PV];
#pragma unroll
  for (int p = 0; p < PV; ++p) {
#pragma unroll
    for (int g = 0; g < 4; ++g) {
      f16x2 w;
      w.x = (f16)W[(2 * p) * 1024 + g * 256 + j];
      w.y = (f16)W[(2 * p + 1) * 1024 + g * 256 + j];
      wreg[g][p] = w;
    }
  }

  if (j < 128) hbuf[0][j] = 0u;
  __syncthreads();

  float c = 0.f;
  float gnext[4];
  {
    const int t0 = dir ? (NN - 1) : 0;
#pragma unroll
    for (int g = 0; g < 4; ++g) gnext[g] = gi[t0 * 1024 + g * 256 + j];
  }
  unsigned cur = 0;

#pragma unroll 1
  for (int s = 0; s < NN; ++s) {
    const int t = dir ? (NN - 1 - s) : s;
    float gcur[4];
#pragma unroll
    for (int g = 0; g < 4; ++g) gcur[g] = gnext[g];
    const int sn = (s + 1 < NN) ? s + 1 : s;
    const int tn = dir ? (NN - 1 - sn) : sn;
#pragma unroll
    for (int g = 0; g < 4; ++g) gnext[g] = gi[tn * 1024 + g * 256 + j];  // prefetch

    float acc[4] = {0.f, 0.f, 0.f, 0.f};
    const uint4* __restrict__ hb = reinterpret_cast<const uint4*>(hbuf[cur]);
#pragma unroll
    for (int pc = 0; pc < PV / 4; ++pc) {
      const uint4 hv = hb[pc];
      const f16x2 h0 = __builtin_bit_cast(f16x2, hv.x);
      const f16x2 h1 = __builtin_bit_cast(f16x2, hv.y);
      const f16x2 h2 = __builtin_bit_cast(f16x2, hv.z);
      const f16x2 h3 = __builtin_bit_cast(f16x2, hv.w);
#pragma unroll
      for (int g = 0; g < 4; ++g) {
        acc[g] = fdot2f(wreg[g][pc * 4 + 0], h0, acc[g]);
        acc[g] = fdot2f(wreg[g][pc * 4 + 1], h1, acc[g]);
        acc[g] = fdot2f(wreg[g][pc * 4 + 2], h2, acc[g]);
        acc[g] = fdot2f(wreg[g][pc * 4 + 3], h3, acc[g]);
      }
    }
#pragma unroll
    for (int ch = 0; ch < PL / 4; ++ch) {
      const uint4 hv = hb[PV / 4 + ch];
      const f16x2 h0 = __builtin_bit_cast(f16x2, hv.x);
      const f16x2 h1 = __builtin_bit_cast(f16x2, hv.y);
      const f16x2 h2 = __builtin_bit_cast(f16x2, hv.z);
      const f16x2 h3 = __builtin_bit_cast(f16x2, hv.w);
#pragma unroll
      for (int g = 0; g < 4; ++g) {
        const uint4 wv = wlds[ch][g][j];
        acc[g] = fdot2f(__builtin_bit_cast(f16x2, wv.x), h0, acc[g]);
        acc[g] = fdot2f(__builtin_bit_cast(f16x2, wv.y), h1, acc[g]);
        acc[g] = fdot2f(__builtin_bit_cast(f16x2, wv.z), h2, acc[g]);
        acc[g] = fdot2f(__builtin_bit_cast(f16x2, wv.w), h3, acc[g]);
      }
    }

    const float iv = sigmoidf_(gcur[0] + acc[0]);
    const float fv = sigmoidf_(gcur[1] + acc[1]);
    const float gv = tanh_fast(gcur[2] + acc[2]);
    const float ov = sigmoidf_(gcur[3] + acc[3]);
    c = fv * c + iv * gv;
    const float hn = ov * tanh_fast(c);

    hcat[t * 512 + dir * 256 + j] = hn;
    reinterpret_cast<f16*>(hbuf[cur ^ 1])[j] = (f16)hn;
    __syncthreads();
    cur ^= 1;
  }
}

// ---------------------------------------------------------------- classifier
__global__ __launch_bounds__(256) void classifier_kernel(
    const float* __restrict__ hq, const float* __restrict__ Wc,
    const float* __restrict__ bc, float* __restrict__ out)
{
  const int m = blockIdx.x;
  const int t = threadIdx.x;
  const float4 hv = reinterpret_cast<const float4*>(hq + (size_t)m * 1024)[t];
  const int k0 = t * 4;
  float acc[5];
#pragma unroll
  for (int jj = 0; jj < 5; ++jj)
    acc[jj] = hv.x * Wc[(k0 + 0) * 5 + jj] + hv.y * Wc[(k0 + 1) * 5 + jj] +
              hv.z * Wc[(k0 + 2) * 5 + jj] + hv.w * Wc[(k0 + 3) * 5 + jj];
#pragma unroll
  for (int off = 32; off > 0; off >>= 1)
#pragma unroll
    for (int jj = 0; jj < 5; ++jj) acc[jj] += __shfl_down(acc[jj], off, 64);
  __shared__ float red[4][5];
  const int lane = t & 63, wid = t >> 6;
  if (lane == 0)
#pragma unroll
    for (int jj = 0; jj < 5; ++jj) red[wid][jj] = acc[jj];
  __syncthreads();
  if (t < 5) out[m * 5 + t] = bc[t] + red[0][t] + red[1][t] + red[2][t] + red[3][t];
}

// ---------------------------------------------------------------- launch
extern "C" void kernel_launch(void* const* d_in, const int* in_sizes, int n_in,
                              void* d_out, int out_size, void* d_ws, size_t ws_size,
                              hipStream_t stream) {
  const float* x     = (const float*)d_in[0];
  const int*   ei    = (const int*)d_in[1];
  const float* Wl1   = (const float*)d_in[2];
  const float* bl1   = (const float*)d_in[3];
  const float* Wr1   = (const float*)d_in[4];
  const float* br1   = (const float*)d_in[5];
  const float* att1  = (const float*)d_in[6];
  const float* bo1   = (const float*)d_in[7];
  const float* Wl2   = (const float*)d_in[8];
  const float* bl2   = (const float*)d_in[9];
  const float* Wr2   = (const float*)d_in[10];
  const float* br2   = (const float*)d_in[11];
  const float* att2  = (const float*)d_in[12];
  const float* bo2   = (const float*)d_in[13];
  const float* Wih_f = (const float*)d_in[14];
  const float* Whh_f = (const float*)d_in[15];
  const float* b_f   = (const float*)d_in[16];
  const float* Wih_b = (const float*)d_in[17];
  const float* Whh_b = (const float*)d_in[18];
  const float* b_b   = (const float*)d_in[19];
  const float* Wq    = (const float*)d_in[20];
  const float* bq    = (const float*)d_in[21];
  const float* Wc    = (const float*)d_in[22];
  const float* bc    = (const float*)d_in[23];
  float* out = (float*)d_out;
  float* ws = (float*)d_ws;

  // workspace layout (float offsets); regions reused once their producer phase ends.
  // total footprint = 19349504 floats = ~77.4 MB
  float* xl1  = ws + 0;         // [4096,1024]  later: hq
  float* xr1  = ws + 4194304;   // [4096,1024]  later: gi_f
  float* out1 = ws + 8388608;   // [4096,1024]  later: gi_b
  float* xl2  = ws + 12582912;  // [4096,512]   later: hcat
  float* xr2  = ws + 14680064;  // [4096,512]
  float* h2   = ws + 16777216;  // [4096,512]
  float* lg1  = ws + 18874368;  // [65536*4]
  float* lg2  = ws + 19136512;  // [65536*2]
  int* rowptr = (int*)(ws + 19267584);  // 4097
  int* counts = (int*)(ws + 19275776);  // 4096
  int* cursor = (int*)(ws + 19279872);  // 4096
  int* eids   = (int*)(ws + 19283968);  // 65536
  float* gi_f = xr1;
  float* gi_b = out1;
  float* hcat = xl2;
  float* hq   = xl1;

  const int* ei_src = ei;
  const int* ei_dst = ei + EE;

  // GAT1 projections
  gat1_proj_kernel<<<dim3(4, NN), 256, 0, stream>>>(x, Wl1, bl1, Wr1, br1, xl1, xr1);

  // CSR by dst (deterministic: lists sorted)
  zero_kernel<<<16, 256, 0, stream>>>(counts, NN);
  hist_kernel<<<EE / 256, 256, 0, stream>>>(ei_dst, counts);
  scan_kernel<<<1, 1024, 0, stream>>>(counts, rowptr);
  copy_kernel<<<16, 256, 0, stream>>>(rowptr, cursor, NN);
  scatter_kernel<<<EE / 256, 256, 0, stream>>>(ei_dst, cursor, eids);
  sortlists_kernel<<<16, 256, 0, stream>>>(rowptr, eids);

  // GAT layer 1
  edge_logits_kernel<4><<<EE * 4 / 4, 256, 0, stream>>>(xl1, xr1, att1, ei, lg1);
  gat_agg_kernel<4, 4><<<NN, 256, 0, stream>>>(xl1, lg1, ei_src, rowptr, eids, bo1, out1);

  // GAT layer 2 projections + edges
  gemm_kernel<0><<<dim3(8, 64), 256, 0, stream>>>(out1, Wl2, bl2, xl2, NN, 512, 1024);
  gemm_kernel<0><<<dim3(8, 64), 256, 0, stream>>>(out1, Wr2, br2, xr2, NN, 512, 1024);
  edge_logits_kernel<2><<<EE * 2 / 4, 256, 0, stream>>>(xl2, xr2, att2, ei, lg2);
  gat_agg_kernel<2, 2><<<NN, 256, 0, stream>>>(xl2, lg2, ei_src, rowptr, eids, bo2, h2);

  // LSTM input projections (out1/xr1 regions are dead now)
  gemm_kernel<0><<<dim3(16, 64), 256, 0, stream>>>(h2, Wih_f, b_f, gi_f, NN, 1024, 512);
  gemm_kernel<0><<<dim3(16, 64), 256, 0, stream>>>(h2, Wih_b, b_b, gi_b, NN, 1024, 512);

  // bidirectional LSTM recurrence -> hcat[t] = [hf[t] | hb[t]]
  lstm_kernel<<<2, 256, 0, stream>>>(gi_f, gi_b, Whh_f, Whh_b, hcat);

  // quantum layer (ELU) + classifier
  gemm_kernel<2><<<dim3(16, 64), 256, 0, stream>>>(hcat, Wq, bq, hq, NN, 1024, 512);
  classifier_kernel<<<NN, 256, 0, stream>>>(hq, Wc, bc, out);
}

// Round 4
// 6981.450 us; speedup vs baseline: 2.0763x; 2.0763x over previous
//
#include <hip/hip_runtime.h>
#include <math.h>

// Problem constants (fixed by the reference)
#define NN 4096
#define EE 65536
#define HDIM 256

typedef _Float16 f16;
typedef f16 f16x2 __attribute__((ext_vector_type(2)));

__device__ inline float fdot2f(f16x2 a, f16x2 b, float c) {
#if __has_builtin(__builtin_amdgcn_fdot2)
  return __builtin_amdgcn_fdot2(a, b, c, false);
#else
  return c + (float)a.x * (float)b.x + (float)a.y * (float)b.y;
#endif
}

__device__ inline float sigmoidf_(float x) { return 1.0f / (1.0f + __expf(-x)); }
__device__ inline float tanh_fast(float x) { return 1.0f - 2.0f / (__expf(2.0f * x) + 1.0f); }

// ---------------------------------------------------------------- GAT1 projection
// xl1 = x@Wl1+bl1 ; xr1 = x@Wr1+br1   (K=14, fused)
__global__ __launch_bounds__(256) void gat1_proj_kernel(
    const float* __restrict__ x,
    const float* __restrict__ Wl, const float* __restrict__ bl,
    const float* __restrict__ Wr, const float* __restrict__ br,
    float* __restrict__ xl1, float* __restrict__ xr1)
{
  const int m = blockIdx.y;
  const int n = blockIdx.x * 256 + threadIdx.x;
  __shared__ float xs[14];
  if (threadIdx.x < 14) xs[threadIdx.x] = x[m * 14 + threadIdx.x];
  __syncthreads();
  float a = bl[n], b = br[n];
#pragma unroll
  for (int k = 0; k < 14; ++k) {
    a = fmaf(xs[k], Wl[k * 1024 + n], a);
    b = fmaf(xs[k], Wr[k * 1024 + n], b);
  }
  xl1[m * 1024 + n] = a;
  xr1[m * 1024 + n] = b;
}

// ---------------------------------------------------------------- CSR build
__global__ void zero_kernel(int* __restrict__ p, int n) {
  int i = blockIdx.x * 256 + threadIdx.x;
  if (i < n) p[i] = 0;
}
__global__ void hist_kernel(const int* __restrict__ dst, int* __restrict__ counts) {
  int e = blockIdx.x * 256 + threadIdx.x;
  if (e < EE) atomicAdd(&counts[dst[e]], 1);
}
__global__ __launch_bounds__(1024) void scan_kernel(const int* __restrict__ counts,
                                                    int* __restrict__ rowptr) {
  __shared__ int s[1024];
  const int t = threadIdx.x;
  const int base = t * 4;
  int v[4];
  int sum = 0;
#pragma unroll
  for (int i = 0; i < 4; ++i) { v[i] = counts[base + i]; sum += v[i]; }
  s[t] = sum;
  __syncthreads();
  for (int off = 1; off < 1024; off <<= 1) {
    int x = (t >= off) ? s[t - off] : 0;
    __syncthreads();
    s[t] += x;
    __syncthreads();
  }
  int run = (t == 0) ? 0 : s[t - 1];
#pragma unroll
  for (int i = 0; i < 4; ++i) { rowptr[base + i] = run; run += v[i]; }
  if (t == 1023) rowptr[4096] = s[1023];
}
__global__ void copy_kernel(const int* __restrict__ a, int* __restrict__ b, int n) {
  int i = blockIdx.x * 256 + threadIdx.x;
  if (i < n) b[i] = a[i];
}
__global__ void scatter_kernel(const int* __restrict__ dst, int* __restrict__ cursor,
                               int* __restrict__ eids) {
  int e = blockIdx.x * 256 + threadIdx.x;
  if (e < EE) {
    int p = atomicAdd(&cursor[dst[e]], 1);
    eids[p] = e;
  }
}
// insertion-sort each dst's edge list -> deterministic FP accumulation order
__global__ void sortlists_kernel(const int* __restrict__ rowptr, int* __restrict__ eids) {
  int d = blockIdx.x * 256 + threadIdx.x;
  if (d >= NN) return;
  const int lo = rowptr[d], hi = rowptr[d + 1];
  for (int i = lo + 1; i < hi; ++i) {
    int key = eids[i];
    int k = i - 1;
    while (k >= lo && eids[k] > key) { eids[k + 1] = eids[k]; --k; }
    eids[k + 1] = key;
  }
}

// ---------------------------------------------------------------- edge logits
// one wave per (edge, head): logit = att[h] . leaky_relu(xl[src,h,:] + xr[dst,h,:])
template <int H>
__global__ __launch_bounds__(256) void edge_logits_kernel(
    const float* __restrict__ xl, const float* __restrict__ xr,
    const float* __restrict__ att, const int* __restrict__ ei,
    float* __restrict__ logits)
{
  const int wid = threadIdx.x >> 6;
  const int lane = threadIdx.x & 63;
  const int task = blockIdx.x * 4 + wid;  // = e*H + h, grid sized exactly
  const int e = task / H;
  const int h = task % H;
  const int src = ei[e];
  const int dst = ei[EE + e];
  const float4 a = reinterpret_cast<const float4*>(xl + (src * H + h) * HDIM)[lane];
  const float4 b = reinterpret_cast<const float4*>(xr + (dst * H + h) * HDIM)[lane];
  const float4 w = reinterpret_cast<const float4*>(att + h * HDIM)[lane];
  float v, acc = 0.f;
  v = a.x + b.x; acc += w.x * (v > 0.f ? v : 0.2f * v);
  v = a.y + b.y; acc += w.y * (v > 0.f ? v : 0.2f * v);
  v = a.z + b.z; acc += w.z * (v > 0.f ? v : 0.2f * v);
  v = a.w + b.w; acc += w.w * (v > 0.f ? v : 0.2f * v);
#pragma unroll
  for (int off = 32; off > 0; off >>= 1) acc += __shfl_down(acc, off, 64);
  if (lane == 0) logits[task] = acc;
}

// ---------------------------------------------------------------- GAT aggregate
template <int H, int VPT>
__global__ __launch_bounds__(256) void gat_agg_kernel(
    const float* __restrict__ xl, const float* __restrict__ logits,
    const int* __restrict__ src_arr, const int* __restrict__ rowptr,
    const int* __restrict__ eids, const float* __restrict__ bias,
    float* __restrict__ out)
{
  const int d = blockIdx.x;
  const int t = threadIdx.x;
  const int TPH = 256 / H;
  const int h = t / TPH;
  const int cb = (t % TPH) * VPT;
  const int ro = rowptr[d];
  const int L = rowptr[d + 1] - ro;

  float m = -INFINITY;
  for (int i = 0; i < L; ++i) m = fmaxf(m, logits[eids[ro + i] * H + h]);
  float denom = 1e-16f;
  for (int i = 0; i < L; ++i) denom += __expf(logits[eids[ro + i] * H + h] - m);
  const float inv = 1.0f / denom;

  float acc[VPT];
#pragma unroll
  for (int v = 0; v < VPT; ++v) acc[v] = 0.f;
  for (int i = 0; i < L; ++i) {
    const int e = eids[ro + i];
    const float p = __expf(logits[e * H + h] - m) * inv;
    const float* px = &xl[(src_arr[e] * H + h) * HDIM + cb];
    if constexpr (VPT == 4) {
      const float4 xv = *reinterpret_cast<const float4*>(px);
      acc[0] += p * xv.x; acc[1] += p * xv.y; acc[2] += p * xv.z; acc[3] += p * xv.w;
    } else {
      const float2 xv = *reinterpret_cast<const float2*>(px);
      acc[0] += p * xv.x; acc[1] += p * xv.y;
    }
  }
#pragma unroll
  for (int v = 0; v < VPT; ++v) {
    const float r = acc[v] + bias[h * HDIM + cb + v];
    out[d * (H * HDIM) + h * HDIM + cb + v] = fmaxf(r, 0.f);
  }
}

// ---------------------------------------------------------------- generic fp32 GEMM
// C[M,N] = act(A[M,K] @ B[K,N] + bias).  ACT: 0 none, 1 relu, 2 elu.
template <int ACT>
__global__ __launch_bounds__(256) void gemm_kernel(
    const float* __restrict__ A, const float* __restrict__ B,
    const float* __restrict__ bias, float* __restrict__ C,
    int M, int N, int K)
{
  __shared__ float As[16][64];
  __shared__ float Bs[16][64];
  const int tid = threadIdx.x;
  const int tx = tid & 15, ty = tid >> 4;
  const int arow = blockIdx.y * 64;
  const int bcol = blockIdx.x * 64;
  const int a_r = tid >> 2;
  const int a_k4 = (tid & 3) * 4;
  const int b_k = tid >> 4;
  const int b_c = (tid & 15) * 4;

  float acc[4][4];
#pragma unroll
  for (int i = 0; i < 4; ++i)
#pragma unroll
    for (int j = 0; j < 4; ++j) acc[i][j] = 0.f;

  for (int k0 = 0; k0 < K; k0 += 16) {
    const float4 av = *reinterpret_cast<const float4*>(&A[(size_t)(arow + a_r) * K + k0 + a_k4]);
    const float4 bv = *reinterpret_cast<const float4*>(&B[(size_t)(k0 + b_k) * N + bcol + b_c]);
    __syncthreads();
    As[a_k4 + 0][a_r] = av.x;
    As[a_k4 + 1][a_r] = av.y;
    As[a_k4 + 2][a_r] = av.z;
    As[a_k4 + 3][a_r] = av.w;
    *reinterpret_cast<float4*>(&Bs[b_k][b_c]) = bv;
    __syncthreads();
#pragma unroll
    for (int k = 0; k < 16; ++k) {
      const float4 a4 = *reinterpret_cast<const float4*>(&As[k][ty * 4]);
      const float4 b4 = *reinterpret_cast<const float4*>(&Bs[k][tx * 4]);
      const float ar[4] = {a4.x, a4.y, a4.z, a4.w};
      const float br[4] = {b4.x, b4.y, b4.z, b4.w};
#pragma unroll
      for (int i = 0; i < 4; ++i)
#pragma unroll
        for (int j = 0; j < 4; ++j) acc[i][j] = fmaf(ar[i], br[j], acc[i][j]);
    }
  }
#pragma unroll
  for (int i = 0; i < 4; ++i) {
    const size_t r = arow + ty * 4 + i;
#pragma unroll
    for (int j = 0; j < 4; ++j) {
      const int ccol = bcol + tx * 4 + j;
      float v = acc[i][j] + bias[ccol];
      if (ACT == 1) v = fmaxf(v, 0.f);
      if (ACT == 2) v = v > 0.f ? v : __expf(v) - 1.f;
      C[r * N + ccol] = v;
    }
  }
}

// ---------------------------------------------------------------- BiLSTM
// grid = 2 blocks (one per direction), 512 threads (8 waves, 2/SIMD).
// Thread t owns gate columns c0=t, c1=t+512 of the 1024 gate dims
// (order i,f,g,o x 256). Per col 128 f16x2 weight pairs:
//   - pairs 0..(4*PVC-1) in VGPRs  (2 cols * 4*PVC words/thread)
//   - pairs 4*PVC..127   in LDS    (full-BW b128 reads, conflict-free)
// h is a 1 KB LDS broadcast buffer (f16x2 packed), double-buffered.
// Gate preacts exchanged via pre[1024] in LDS; 2 barriers/step.
#define LT 512
#define PVC 25  // uint4 chunks (4 pairs) per col in VGPR  -> 100 pairs, 200 words/thread
#define PLC 7   // uint4 chunks per col in LDS             -> 28 pairs, 112 KB total

__global__ __launch_bounds__(LT, 2) void lstm_kernel(
    const float* __restrict__ gi_f, const float* __restrict__ gi_b,
    const float* __restrict__ Whh_f, const float* __restrict__ Whh_b,
    float* __restrict__ hcat)
{
  const int dir = blockIdx.x;
  const float* __restrict__ gi = dir ? gi_b : gi_f;
  const float* __restrict__ W = dir ? Whh_b : Whh_f;
  const int t = threadIdx.x;
  const int c0 = t;
  const int c1 = t + LT;

  __shared__ uint4 wlds[2][PLC][LT];   // 112 KiB
  __shared__ uint4 hbuf[2][32];        // 1 KiB (256 f16 per buffer)
  __shared__ float pre[1024];          // 4 KiB

  // VGPR-resident weights: pairs p = 0 .. 4*PVC-1
  f16x2 wA[PVC][4], wB[PVC][4];
#pragma unroll
  for (int ch = 0; ch < PVC; ++ch) {
#pragma unroll
    for (int pi = 0; pi < 4; ++pi) {
      const int p = ch * 4 + pi;
      f16x2 wa, wb;
      wa.x = (f16)W[(2 * p) * 1024 + c0];
      wa.y = (f16)W[(2 * p + 1) * 1024 + c0];
      wb.x = (f16)W[(2 * p) * 1024 + c1];
      wb.y = (f16)W[(2 * p + 1) * 1024 + c1];
      wA[ch][pi] = wa;
      wB[ch][pi] = wb;
    }
  }
  // LDS-resident weights: pairs p = 4*PVC .. 127
#pragma unroll
  for (int ch = 0; ch < PLC; ++ch) {
    uint4 va, vb;
    unsigned* pa = reinterpret_cast<unsigned*>(&va);
    unsigned* pb = reinterpret_cast<unsigned*>(&vb);
#pragma unroll
    for (int pi = 0; pi < 4; ++pi) {
      const int p = 4 * PVC + ch * 4 + pi;
      f16x2 wa, wb;
      wa.x = (f16)W[(2 * p) * 1024 + c0];
      wa.y = (f16)W[(2 * p + 1) * 1024 + c0];
      wb.x = (f16)W[(2 * p) * 1024 + c1];
      wb.y = (f16)W[(2 * p + 1) * 1024 + c1];
      pa[pi] = __builtin_bit_cast(unsigned, wa);
      pb[pi] = __builtin_bit_cast(unsigned, wb);
    }
    wlds[0][ch][t] = va;
    wlds[1][ch][t] = vb;
  }

  if (t < 32) hbuf[0][t] = make_uint4(0u, 0u, 0u, 0u);
  __syncthreads();

  float cst = 0.f;  // cell state, valid for t < 256
  float gn0, gn1;
  {
    const int t0 = dir ? (NN - 1) : 0;
    gn0 = gi[t0 * 1024 + c0];
    gn1 = gi[t0 * 1024 + c1];
  }
  unsigned cur = 0;

#pragma unroll 1
  for (int s = 0; s < NN; ++s) {
    const int ts = dir ? (NN - 1 - s) : s;
    const float gc0 = gn0, gc1 = gn1;
    const int sn = (s + 1 < NN) ? s + 1 : s;
    const int tn = dir ? (NN - 1 - sn) : sn;
    gn0 = gi[tn * 1024 + c0];  // prefetch next step's input projections
    gn1 = gi[tn * 1024 + c1];

    float acc0 = 0.f, acc1 = 0.f;
    const uint4* __restrict__ hb = hbuf[cur];
#pragma unroll
    for (int ch = 0; ch < PVC; ++ch) {
      const uint4 hv = hb[ch];
      const f16x2 h0 = __builtin_bit_cast(f16x2, hv.x);
      const f16x2 h1 = __builtin_bit_cast(f16x2, hv.y);
      const f16x2 h2 = __builtin_bit_cast(f16x2, hv.z);
      const f16x2 h3 = __builtin_bit_cast(f16x2, hv.w);
      acc0 = fdot2f(wA[ch][0], h0, acc0);
      acc0 = fdot2f(wA[ch][1], h1, acc0);
      acc0 = fdot2f(wA[ch][2], h2, acc0);
      acc0 = fdot2f(wA[ch][3], h3, acc0);
      acc1 = fdot2f(wB[ch][0], h0, acc1);
      acc1 = fdot2f(wB[ch][1], h1, acc1);
      acc1 = fdot2f(wB[ch][2], h2, acc1);
      acc1 = fdot2f(wB[ch][3], h3, acc1);
    }
#pragma unroll
    for (int ch = 0; ch < PLC; ++ch) {
      const uint4 hv = hb[PVC + ch];
      const f16x2 h0 = __builtin_bit_cast(f16x2, hv.x);
      const f16x2 h1 = __builtin_bit_cast(f16x2, hv.y);
      const f16x2 h2 = __builtin_bit_cast(f16x2, hv.z);
      const f16x2 h3 = __builtin_bit_cast(f16x2, hv.w);
      const uint4 va = wlds[0][ch][t];
      const uint4 vb = wlds[1][ch][t];
      acc0 = fdot2f(__builtin_bit_cast(f16x2, va.x), h0, acc0);
      acc0 = fdot2f(__builtin_bit_cast(f16x2, va.y), h1, acc0);
      acc0 = fdot2f(__builtin_bit_cast(f16x2, va.z), h2, acc0);
      acc0 = fdot2f(__builtin_bit_cast(f16x2, va.w), h3, acc0);
      acc1 = fdot2f(__builtin_bit_cast(f16x2, vb.x), h0, acc1);
      acc1 = fdot2f(__builtin_bit_cast(f16x2, vb.y), h1, acc1);
      acc1 = fdot2f(__builtin_bit_cast(f16x2, vb.z), h2, acc1);
      acc1 = fdot2f(__builtin_bit_cast(f16x2, vb.w), h3, acc1);
    }

    pre[c0] = gc0 + acc0;
    pre[c1] = gc1 + acc1;
    __syncthreads();

    if (t < 256) {
      const float iv = sigmoidf_(pre[t]);
      const float fv = sigmoidf_(pre[t + 256]);
      const float gv = tanh_fast(pre[t + 512]);
      const float ov = sigmoidf_(pre[t + 768]);
      cst = fv * cst + iv * gv;
      const float hn = ov * tanh_fast(cst);
      hcat[ts * 512 + dir * 256 + t] = hn;
      reinterpret_cast<f16*>(&hbuf[cur ^ 1][0])[t] = (f16)hn;
    }
    __syncthreads();
    cur ^= 1;
  }
}

// ---------------------------------------------------------------- classifier
__global__ __launch_bounds__(256) void classifier_kernel(
    const float* __restrict__ hq, const float* __restrict__ Wc,
    const float* __restrict__ bc, float* __restrict__ out)
{
  const int m = blockIdx.x;
  const int t = threadIdx.x;
  const float4 hv = reinterpret_cast<const float4*>(hq + (size_t)m * 1024)[t];
  const int k0 = t * 4;
  float acc[5];
#pragma unroll
  for (int jj = 0; jj < 5; ++jj)
    acc[jj] = hv.x * Wc[(k0 + 0) * 5 + jj] + hv.y * Wc[(k0 + 1) * 5 + jj] +
              hv.z * Wc[(k0 + 2) * 5 + jj] + hv.w * Wc[(k0 + 3) * 5 + jj];
#pragma unroll
  for (int off = 32; off > 0; off >>= 1)
#pragma unroll
    for (int jj = 0; jj < 5; ++jj) acc[jj] += __shfl_down(acc[jj], off, 64);
  __shared__ float red[4][5];
  const int lane = t & 63, wid = t >> 6;
  if (lane == 0)
#pragma unroll
    for (int jj = 0; jj < 5; ++jj) red[wid][jj] = acc[jj];
  __syncthreads();
  if (t < 5) out[m * 5 + t] = bc[t] + red[0][t] + red[1][t] + red[2][t] + red[3][t];
}

// ---------------------------------------------------------------- launch
extern "C" void kernel_launch(void* const* d_in, const int* in_sizes, int n_in,
                              void* d_out, int out_size, void* d_ws, size_t ws_size,
                              hipStream_t stream) {
  const float* x     = (const float*)d_in[0];
  const int*   ei    = (const int*)d_in[1];
  const float* Wl1   = (const float*)d_in[2];
  const float* bl1   = (const float*)d_in[3];
  const float* Wr1   = (const float*)d_in[4];
  const float* br1   = (const float*)d_in[5];
  const float* att1  = (const float*)d_in[6];
  const float* bo1   = (const float*)d_in[7];
  const float* Wl2   = (const float*)d_in[8];
  const float* bl2   = (const float*)d_in[9];
  const float* Wr2   = (const float*)d_in[10];
  const float* br2   = (const float*)d_in[11];
  const float* att2  = (const float*)d_in[12];
  const float* bo2   = (const float*)d_in[13];
  const float* Wih_f = (const float*)d_in[14];
  const float* Whh_f = (const float*)d_in[15];
  const float* b_f   = (const float*)d_in[16];
  const float* Wih_b = (const float*)d_in[17];
  const float* Whh_b = (const float*)d_in[18];
  const float* b_b   = (const float*)d_in[19];
  const float* Wq    = (const float*)d_in[20];
  const float* bq    = (const float*)d_in[21];
  const float* Wc    = (const float*)d_in[22];
  const float* bc    = (const float*)d_in[23];
  float* out = (float*)d_out;
  float* ws = (float*)d_ws;

  // workspace layout (float offsets); regions reused once their producer phase ends.
  float* xl1  = ws + 0;         // [4096,1024]  later: hq
  float* xr1  = ws + 4194304;   // [4096,1024]  later: gi_f
  float* out1 = ws + 8388608;   // [4096,1024]  later: gi_b
  float* xl2  = ws + 12582912;  // [4096,512]   later: hcat
  float* xr2  = ws + 14680064;  // [4096,512]
  float* h2   = ws + 16777216;  // [4096,512]
  float* lg1  = ws + 18874368;  // [65536*4]
  float* lg2  = ws + 19136512;  // [65536*2]
  int* rowptr = (int*)(ws + 19267584);  // 4097
  int* counts = (int*)(ws + 19275776);  // 4096
  int* cursor = (int*)(ws + 19279872);  // 4096
  int* eids   = (int*)(ws + 19283968);  // 65536
  float* gi_f = xr1;
  float* gi_b = out1;
  float* hcat = xl2;
  float* hq   = xl1;

  const int* ei_src = ei;
  const int* ei_dst = ei + EE;

  // GAT1 projections
  gat1_proj_kernel<<<dim3(4, NN), 256, 0, stream>>>(x, Wl1, bl1, Wr1, br1, xl1, xr1);

  // CSR by dst (deterministic: lists sorted)
  zero_kernel<<<16, 256, 0, stream>>>(counts, NN);
  hist_kernel<<<EE / 256, 256, 0, stream>>>(ei_dst, counts);
  scan_kernel<<<1, 1024, 0, stream>>>(counts, rowptr);
  copy_kernel<<<16, 256, 0, stream>>>(rowptr, cursor, NN);
  scatter_kernel<<<EE / 256, 256, 0, stream>>>(ei_dst, cursor, eids);
  sortlists_kernel<<<16, 256, 0, stream>>>(rowptr, eids);

  // GAT layer 1
  edge_logits_kernel<4><<<EE * 4 / 4, 256, 0, stream>>>(xl1, xr1, att1, ei, lg1);
  gat_agg_kernel<4, 4><<<NN, 256, 0, stream>>>(xl1, lg1, ei_src, rowptr, eids, bo1, out1);

  // GAT layer 2 projections + edges
  gemm_kernel<0><<<dim3(8, 64), 256, 0, stream>>>(out1, Wl2, bl2, xl2, NN, 512, 1024);
  gemm_kernel<0><<<dim3(8, 64), 256, 0, stream>>>(out1, Wr2, br2, xr2, NN, 512, 1024);
  edge_logits_kernel<2><<<EE * 2 / 4, 256, 0, stream>>>(xl2, xr2, att2, ei, lg2);
  gat_agg_kernel<2, 2><<<NN, 256, 0, stream>>>(xl2, lg2, ei_src, rowptr, eids, bo2, h2);

  // LSTM input projections (out1/xr1 regions are dead now)
  gemm_kernel<0><<<dim3(16, 64), 256, 0, stream>>>(h2, Wih_f, b_f, gi_f, NN, 1024, 512);
  gemm_kernel<0><<<dim3(16, 64), 256, 0, stream>>>(h2, Wih_b, b_b, gi_b, NN, 1024, 512);

  // bidirectional LSTM recurrence -> hcat[t] = [hf[t] | hb[t]]
  lstm_kernel<<<2, LT, 0, stream>>>(gi_f, gi_b, Whh_f, Whh_b, hcat);

  // quantum layer (ELU) + classifier
  gemm_kernel<2><<<dim3(16, 64), 256, 0, stream>>>(hcat, Wq, bq, hq, NN, 1024, 512);
  classifier_kernel<<<NN, 256, 0, stream>>>(hq, Wc, bc, out);
}